// Round 10
// baseline (1058.559 us; speedup 1.0000x reference)
//
#include <hip/hip_runtime.h>
#include <cmath>

#define HIDC   128
#define LAYERS 4
#define IN_C   64
#define OUT_C  64

typedef _Float16 h16x8 __attribute__((ext_vector_type(8)));
typedef _Float16 h16x2 __attribute__((ext_vector_type(2)));
typedef float    f32x4 __attribute__((ext_vector_type(4)));

__device__ __forceinline__ float gelu_f(float x) {
    return 0.5f * x * (1.0f + erff(x * 0.70710678118654752f));
}

__device__ __forceinline__ void cvt8(const float4& a, const float4& b, h16x8& h) {
    h[0]=(_Float16)a.x; h[1]=(_Float16)a.y; h[2]=(_Float16)a.z; h[3]=(_Float16)a.w;
    h[4]=(_Float16)b.x; h[5]=(_Float16)b.y; h[6]=(_Float16)b.z; h[7]=(_Float16)b.w;
}
__device__ __forceinline__ void load16(const float* p, _Float16* d) {
    float4 v0 = *(const float4*)p,     v1 = *(const float4*)(p + 4);
    float4 v2 = *(const float4*)(p+8), v3 = *(const float4*)(p + 12);
    h16x8 h0, h1; cvt8(v0, v1, h0); cvt8(v2, v3, h1);
    *(h16x8*)d = h0; *(h16x8*)(d + 8) = h1;
}
__device__ __forceinline__ void load16(const _Float16* p, _Float16* d) {
    *(h16x8*)d = *(const h16x8*)p; *(h16x8*)(d + 8) = *(const h16x8*)(p + 8);
}
__device__ __forceinline__ void zero16(_Float16* d) {
    h16x8 z = {};
    *(h16x8*)d = z; *(h16x8*)(d + 8) = z;
}

// ------------------------------ CSR build ------------------------------
__global__ void count_deg_k(const int* __restrict__ dst, int* __restrict__ cnt, int E) {
    int i = blockIdx.x * blockDim.x + threadIdx.x;
    if (i < E) atomicAdd(&cnt[dst[i]], 1);
}

// 3-phase parallel exclusive scan over cnt[n] -> rowptr[n] (+ rowptr[n]=E)
__global__ __launch_bounds__(256)
void scan1_k(const int* __restrict__ cnt, int* __restrict__ pref,
             int* __restrict__ bsum, int n) {
    __shared__ int part[256];
    const int b = blockIdx.x, t = threadIdx.x;
    const int i0 = b * 1024 + t * 4;
    int v0 = (i0 + 0 < n) ? cnt[i0 + 0] : 0;
    int v1 = (i0 + 1 < n) ? cnt[i0 + 1] : 0;
    int v2 = (i0 + 2 < n) ? cnt[i0 + 2] : 0;
    int v3 = (i0 + 3 < n) ? cnt[i0 + 3] : 0;
    int s = v0 + v1 + v2 + v3;
    part[t] = s;
    __syncthreads();
    for (int off = 1; off < 256; off <<= 1) {
        int x = (t >= off) ? part[t - off] : 0;
        __syncthreads();
        part[t] += x;
        __syncthreads();
    }
    int excl = part[t] - s;   // exclusive prefix within block
    if (i0 + 0 < n) pref[i0 + 0] = excl;           excl += v0;
    if (i0 + 1 < n) pref[i0 + 1] = excl;           excl += v1;
    if (i0 + 2 < n) pref[i0 + 2] = excl;           excl += v2;
    if (i0 + 3 < n) pref[i0 + 3] = excl;
    if (t == 255) bsum[b] = part[255];
}

__global__ void scan2_k(const int* __restrict__ bsum, int* __restrict__ boff,
                        int nb, int* __restrict__ rowptr_n) {
    int lane = threadIdx.x;  // blockDim = 64, one wave
    int carry = 0;
    for (int base = 0; base < nb; base += 64) {
        int i = base + lane;
        int v = (i < nb) ? bsum[i] : 0;
        int incl = v;
        for (int off = 1; off < 64; off <<= 1) {
            int x = __shfl_up(incl, off);
            if (lane >= off) incl += x;
        }
        if (i < nb) boff[i] = carry + incl - v;
        carry += __shfl(incl, 63);
    }
    if (lane == 0) *rowptr_n = carry;   // = E
}

__global__ __launch_bounds__(256)
void scan3_k(int* __restrict__ pref, const int* __restrict__ boff, int n) {
    int i = blockIdx.x * blockDim.x + threadIdx.x;
    if (i < n) pref[i] += boff[i >> 10];
}

__global__ void scatter_k(const int* __restrict__ src, const int* __restrict__ dst,
                          const int* __restrict__ rowptr, int* __restrict__ cnt,
                          int* __restrict__ csrc, int E) {
    int i = blockIdx.x * blockDim.x + threadIdx.x;
    if (i < E) {
        int d = dst[i];
        int pos = rowptr[d] + atomicAdd(&cnt[d], 1);
        csrc[pos] = src[i];
    }
}

// --------------- generic MFMA fp16 GEMM: C = A @ W^T + bias (+gelu)(+res) --
template<int ACT, bool RES, bool NGUARD, typename AT, typename CT>
__device__ __forceinline__ void gemm_core(
    const AT* __restrict__ A, const float* __restrict__ Wt,
    const float* __restrict__ bias, const float* __restrict__ resid,
    CT* __restrict__ Ct, int M, int K, int ncs, int colbase, int nclim)
{
    __shared__ __align__(16) _Float16 As[128 * 40];
    __shared__ __align__(16) _Float16 Bs[128 * 40];
    const int tid  = threadIdx.x;
    const int lane = tid & 63;
    const int wave = tid >> 6;
    const int wr = wave >> 1, wc = wave & 1;
    const int row0 = blockIdx.y * 128;

    f32x4 acc[4][4] = {};

    const int srow = tid >> 1;
    const int skc  = (tid & 1) * 16;
    const int fr   = lane & 15;
    const int fk   = (lane >> 4) * 8;

    for (int k0 = 0; k0 < K; k0 += 32) {
        {
            int gr = row0 + srow;
            _Float16* d = As + srow * 40 + skc;
            if (gr < M) load16(A + (size_t)gr * K + k0 + skc, d);
            else        zero16(d);
        }
        {
            int gc = colbase + srow;
            _Float16* d = Bs + srow * 40 + skc;
            if (!NGUARD || gc < nclim) load16(Wt + (size_t)gc * K + k0 + skc, d);
            else                       zero16(d);
        }
        __syncthreads();
        h16x8 af[4], bf[4];
#pragma unroll
        for (int mi = 0; mi < 4; ++mi)
            af[mi] = *(const h16x8*)(As + (wr * 64 + mi * 16 + fr) * 40 + fk);
#pragma unroll
        for (int ni = 0; ni < 4; ++ni)
            bf[ni] = *(const h16x8*)(Bs + (wc * 64 + ni * 16 + fr) * 40 + fk);
#pragma unroll
        for (int mi = 0; mi < 4; ++mi)
#pragma unroll
            for (int ni = 0; ni < 4; ++ni)
                acc[mi][ni] = __builtin_amdgcn_mfma_f32_16x16x32_f16(af[mi], bf[ni], acc[mi][ni], 0, 0, 0);
        __syncthreads();
    }

    const int rbase = row0 + wr * 64 + ((lane >> 4) * 4);
    const int cbase = colbase + wc * 64 + fr;
#pragma unroll
    for (int mi = 0; mi < 4; ++mi) {
#pragma unroll
        for (int j = 0; j < 4; ++j) {
            int r = rbase + mi * 16 + j;
            if (r >= M) continue;
            size_t rb = (size_t)r * ncs;
#pragma unroll
            for (int ni = 0; ni < 4; ++ni) {
                int c = cbase + ni * 16;
                if (NGUARD && c >= nclim) continue;
                float v = acc[mi][ni][j] + bias[c];
                if (ACT == 1) v = gelu_f(v);
                if (RES) v += resid[rb + c];
                Ct[rb + c] = (CT)v;
            }
        }
    }
}

template<int ACT, bool RES, bool NGUARD, typename AT, typename CT>
__global__ __launch_bounds__(256)
void gemm_f16_k(const AT* __restrict__ A, const float* __restrict__ W,
                const float* __restrict__ bias, const float* __restrict__ resid,
                CT* __restrict__ C, int M, int NC, int K) {
    gemm_core<ACT, RES, NGUARD, AT, CT>(A, W, bias, resid, C, M, K, NC, blockIdx.x * 128, NC);
}

// --------- fused Q/K/V/S: stage A once, loop 4 weight sets ------------------
// outputs: qh fp16 [N,128]; kv fp16 [N,256] (k|v); sb fp32 [N,128]
__global__ __launch_bounds__(256)
void qkvs_k(const float* __restrict__ A,
            const float* __restrict__ Wq, const float* __restrict__ Wk,
            const float* __restrict__ Wv, const float* __restrict__ Wvs,
            const float* __restrict__ bq, const float* __restrict__ bk,
            const float* __restrict__ bv, const float* __restrict__ bs,
            _Float16* __restrict__ qh, _Float16* __restrict__ kv,
            float* __restrict__ sb, int M) {
    __shared__ __align__(16) _Float16 As[128 * 136];
    __shared__ __align__(16) _Float16 Bs[128 * 136];
    const int tid  = threadIdx.x;
    const int lane = tid & 63;
    const int wave = tid >> 6;
    const int wr = wave >> 1, wc = wave & 1;
    const int row0 = blockIdx.x * 128;
    const int srow  = tid >> 1;
    const int shalf = (tid & 1) * 64;
    const int fr = lane & 15;

    {
        int gr = row0 + srow;
        _Float16* d = As + srow * 136 + shalf;
        if (gr < M) {
            const float* p = A + (size_t)gr * 128 + shalf;
#pragma unroll
            for (int u = 0; u < 4; ++u) load16(p + u * 16, d + u * 16);
        } else {
#pragma unroll
            for (int u = 0; u < 4; ++u) zero16(d + u * 16);
        }
    }

    for (int w = 0; w < 4; ++w) {
        const float* Wp = (w == 0) ? Wq : (w == 1) ? Wk : (w == 2) ? Wv : Wvs;
        const float* bp = (w == 0) ? bq : (w == 1) ? bk : (w == 2) ? bv : bs;
        {
            const float* p = Wp + (size_t)srow * 128 + shalf;
            _Float16* d = Bs + srow * 136 + shalf;
#pragma unroll
            for (int u = 0; u < 4; ++u) load16(p + u * 16, d + u * 16);
        }
        __syncthreads();
        f32x4 acc[4][4] = {};
#pragma unroll
        for (int ks = 0; ks < 4; ++ks) {
            const int fk = ks * 32 + (lane >> 4) * 8;
            h16x8 af[4], bf[4];
#pragma unroll
            for (int mi = 0; mi < 4; ++mi)
                af[mi] = *(const h16x8*)(As + (wr * 64 + mi * 16 + fr) * 136 + fk);
#pragma unroll
            for (int ni = 0; ni < 4; ++ni)
                bf[ni] = *(const h16x8*)(Bs + (wc * 64 + ni * 16 + fr) * 136 + fk);
#pragma unroll
            for (int mi = 0; mi < 4; ++mi)
#pragma unroll
                for (int ni = 0; ni < 4; ++ni)
                    acc[mi][ni] = __builtin_amdgcn_mfma_f32_16x16x32_f16(af[mi], bf[ni], acc[mi][ni], 0, 0, 0);
        }
        __syncthreads();

        const int rbase = row0 + wr * 64 + ((lane >> 4) * 4);
        const int cbase = wc * 64 + fr;
#pragma unroll
        for (int mi = 0; mi < 4; ++mi) {
#pragma unroll
            for (int j = 0; j < 4; ++j) {
                int r = rbase + mi * 16 + j;
                if (r >= M) continue;
#pragma unroll
                for (int ni = 0; ni < 4; ++ni) {
                    int c = cbase + ni * 16;
                    float v = acc[mi][ni][j] + bp[c];
                    if (w == 0)      qh[(size_t)r * 128 + c] = (_Float16)v;
                    else if (w == 1) kv[(size_t)r * 256 + c] = (_Float16)v;
                    else if (w == 2) kv[(size_t)r * 256 + 128 + c] = (_Float16)v;
                    else             sb[(size_t)r * 128 + c] = v;
                }
            }
        }
    }
}

// --------- FFN1 single-A-pass: stage h2 tile once, loop 4 slabs of W1 -------
// out: ffn fp16 [N,512] = gelu(h2 @ W1^T + b1)
__global__ __launch_bounds__(256)
void ffn1_k(const float* __restrict__ A, const float* __restrict__ W1,
            const float* __restrict__ b1, _Float16* __restrict__ ffn, int M) {
    __shared__ __align__(16) _Float16 As[128 * 136];
    __shared__ __align__(16) _Float16 Bs[128 * 136];
    const int tid  = threadIdx.x;
    const int lane = tid & 63;
    const int wave = tid >> 6;
    const int wr = wave >> 1, wc = wave & 1;
    const int row0 = blockIdx.x * 128;
    const int srow  = tid >> 1;
    const int shalf = (tid & 1) * 64;
    const int fr = lane & 15;

    {
        int gr = row0 + srow;
        _Float16* d = As + srow * 136 + shalf;
        if (gr < M) {
            const float* p = A + (size_t)gr * 128 + shalf;
#pragma unroll
            for (int u = 0; u < 4; ++u) load16(p + u * 16, d + u * 16);
        } else {
#pragma unroll
            for (int u = 0; u < 4; ++u) zero16(d + u * 16);
        }
    }

    for (int w = 0; w < 4; ++w) {
        const float* Wp = W1 + (size_t)w * 128 * 128;   // rows 128w..128w+127
        {
            const float* p = Wp + (size_t)srow * 128 + shalf;
            _Float16* d = Bs + srow * 136 + shalf;
#pragma unroll
            for (int u = 0; u < 4; ++u) load16(p + u * 16, d + u * 16);
        }
        __syncthreads();
        f32x4 acc[4][4] = {};
#pragma unroll
        for (int ks = 0; ks < 4; ++ks) {
            const int fk = ks * 32 + (lane >> 4) * 8;
            h16x8 af[4], bf[4];
#pragma unroll
            for (int mi = 0; mi < 4; ++mi)
                af[mi] = *(const h16x8*)(As + (wr * 64 + mi * 16 + fr) * 136 + fk);
#pragma unroll
            for (int ni = 0; ni < 4; ++ni)
                bf[ni] = *(const h16x8*)(Bs + (wc * 64 + ni * 16 + fr) * 136 + fk);
#pragma unroll
            for (int mi = 0; mi < 4; ++mi)
#pragma unroll
                for (int ni = 0; ni < 4; ++ni)
                    acc[mi][ni] = __builtin_amdgcn_mfma_f32_16x16x32_f16(af[mi], bf[ni], acc[mi][ni], 0, 0, 0);
        }
        __syncthreads();

        const int rbase = row0 + wr * 64 + ((lane >> 4) * 4);
        const int cbase = wc * 64 + fr;
#pragma unroll
        for (int mi = 0; mi < 4; ++mi) {
#pragma unroll
            for (int j = 0; j < 4; ++j) {
                int r = rbase + mi * 16 + j;
                if (r >= M) continue;
#pragma unroll
                for (int ni = 0; ni < 4; ++ni) {
                    int c = cbase + ni * 16;
                    float v = acc[mi][ni][j] + b1[w * 128 + c];
                    ffn[(size_t)r * 512 + w * 128 + c] = (_Float16)gelu_f(v);
                }
            }
        }
    }
}

// ---- fused attention + beta gate + residual + LN -------------------------
__global__ __launch_bounds__(256)
void attn_ln_k(const _Float16* __restrict__ qh, const _Float16* __restrict__ kv,
               const int* __restrict__ rowptr, const int* __restrict__ csrc,
               const float* __restrict__ xr, const float* __restrict__ res,
               const float* __restrict__ Wb, const float* __restrict__ g_,
               const float* __restrict__ b_, float* __restrict__ out, int n) {
    int node = (int)((blockIdx.x * (size_t)blockDim.x + threadIdx.x) >> 6);
    int lane = threadIdx.x & 63;
    if (node >= n) return;
    const int g = lane & 7;     // edge slot
    const int h = lane >> 3;    // head

    const _Float16* qp = qh + (size_t)node * 128 + h * 16;
    h16x8 q0 = *(const h16x8*)(qp);
    h16x8 q1 = *(const h16x8*)(qp + 8);

    float ssum = 0.f;
    float acc[16] = {};
    const int e0 = rowptr[node], e1 = rowptr[node + 1];
    for (int eb = e0; eb < e1; eb += 8) {
        int e = eb + g;
        bool val = (e < e1);
        int s = csrc[val ? e : (e1 - 1)];
        const _Float16* kp = kv + (size_t)s * 256 + h * 16;
        h16x8 k0 = *(const h16x8*)(kp);
        h16x8 k1 = *(const h16x8*)(kp + 8);
        h16x8 v0 = *(const h16x8*)(kp + 128);
        h16x8 v1 = *(const h16x8*)(kp + 136);
        float d = 0.f;
#pragma unroll
        for (int j = 0; j < 8; ++j) d += (float)k0[j] * (float)q0[j];
#pragma unroll
        for (int j = 0; j < 8; ++j) d += (float)k1[j] * (float)q1[j];
        float w = val ? __expf(d * 0.25f) : 0.f;
        ssum += w;
#pragma unroll
        for (int j = 0; j < 8; ++j) acc[j]     += w * (float)v0[j];
#pragma unroll
        for (int j = 0; j < 8; ++j) acc[8 + j] += w * (float)v1[j];
    }
#pragma unroll
    for (int m = 1; m < 8; m <<= 1) {
        ssum += __shfl_xor(ssum, m);
#pragma unroll
        for (int j = 0; j < 16; ++j) acc[j] += __shfl_xor(acc[j], m);
    }
    float inv = 1.f / (ssum + 1e-16f);
    const bool s0b = g & 1, s1b = g & 2, s2b = g & 4;
    float t0 = s0b ? acc[2]  : acc[0],  t1 = s0b ? acc[6]  : acc[4];
    float t2 = s0b ? acc[10] : acc[8],  t3 = s0b ? acc[14] : acc[12];
    float u0 = s1b ? t1 : t0,           u1 = s1b ? t3 : t2;
    float ox = (s2b ? u1 : u0) * inv;
    float p0 = s0b ? acc[3]  : acc[1],  p1 = s0b ? acc[7]  : acc[5];
    float p2 = s0b ? acc[11] : acc[9],  p3 = s0b ? acc[15] : acc[13];
    float w0 = s1b ? p1 : p0,           w1 = s1b ? p3 : p2;
    float oy = (s2b ? w1 : w0) * inv;

    size_t base = (size_t)node * HIDC + lane * 2;
    int c = lane * 2;
    float2 r  = *(const float2*)(xr + base);
    float2 wb0 = *(const float2*)(Wb + c);
    float2 wb1 = *(const float2*)(Wb + HIDC + c);
    float2 wb2 = *(const float2*)(Wb + 2 * HIDC + c);
    float part = ox * wb0.x + oy * wb0.y
               + r.x * wb1.x + r.y * wb1.y
               + (ox - r.x) * wb2.x + (oy - r.y) * wb2.y;
#pragma unroll
    for (int mk = 1; mk < 64; mk <<= 1) part += __shfl_xor(part, mk);
    float beta = 1.f / (1.f + __expf(-part));
    float2 rs = *(const float2*)(res + base);
    float tx = beta * r.x + (1.f - beta) * ox + rs.x;
    float ty = beta * r.y + (1.f - beta) * oy + rs.y;
    float sum = tx + ty;
#pragma unroll
    for (int mk = 1; mk < 64; mk <<= 1) sum += __shfl_xor(sum, mk);
    float mean = sum * (1.f / 128.f);
    float dx = tx - mean, dy = ty - mean;
    float vs = dx * dx + dy * dy;
#pragma unroll
    for (int mk = 1; mk < 64; mk <<= 1) vs += __shfl_xor(vs, mk);
    float rstd = 1.f / sqrtf(vs * (1.f / 128.f) + 1e-5f);
    float2 gg = *(const float2*)(g_ + c);
    float2 bb = *(const float2*)(b_ + c);
    float2 oo = make_float2(dx * rstd * gg.x + bb.x, dy * rstd * gg.y + bb.y);
    *(float2*)(out + base) = oo;
}

// ------------------------------ host launch ------------------------------
extern "C" void kernel_launch(void* const* d_in, const int* in_sizes, int n_in,
                              void* d_out, int out_size, void* d_ws, size_t ws_size,
                              hipStream_t stream) {
    const float* x    = (const float*)d_in[0];
    const int*   ei   = (const int*)d_in[1];
    const float* Wi   = (const float*)d_in[2];
    const float* bi   = (const float*)d_in[3];
    const float* Wq   = (const float*)d_in[4];
    const float* bq   = (const float*)d_in[5];
    const float* Wk   = (const float*)d_in[6];
    const float* bk   = (const float*)d_in[7];
    const float* Wv   = (const float*)d_in[8];
    const float* bv   = (const float*)d_in[9];
    const float* Ws_  = (const float*)d_in[10];
    const float* bs   = (const float*)d_in[11];
    const float* Wbeta= (const float*)d_in[12];
    const float* ln_g = (const float*)d_in[13];
    const float* ln_b = (const float*)d_in[14];
    const float* W1   = (const float*)d_in[15];
    const float* b1   = (const float*)d_in[16];
    const float* W2   = (const float*)d_in[17];
    const float* b2   = (const float*)d_in[18];
    const float* Wo   = (const float*)d_in[19];
    const float* bo   = (const float*)d_in[20];
    float* outp = (float*)d_out;

    const int Nn = in_sizes[0] / IN_C;   // 50000
    const int Ee = in_sizes[1] / 2;      // 600000
    const int* srcI = ei;
    const int* dstI = ei + Ee;

    // ws: h(1) | h2(1) | qh(0.5) | kv(1) | sb(1) [n128 units] | ints
    float* ws = (float*)d_ws;
    size_t n128 = (size_t)Nn * HIDC;
    float*     h   = ws;
    float*     h2  = h  + n128;
    _Float16*  qh  = (_Float16*)(h2 + n128);       // N*128 f16
    _Float16*  kv  = qh + (size_t)Nn * 128;        // N*256 f16
    float*     sb  = (float*)(kv + (size_t)Nn * 256);
    _Float16*  ffn = qh;                           // [N,512] f16 aliases qh|kv|sb
    int* rowptr = (int*)(sb + n128);               // N+1
    int* cnt    = rowptr + (Nn + 1);               // N
    int* csrc   = cnt + Nn;                        // E
    int* bsum   = csrc + Ee;                       // <=1024
    int* boff   = bsum + 1024;                     // <=1024

    const int nb = (Nn + 1023) / 1024;             // scan blocks (49)

    hipMemsetAsync(cnt, 0, Nn * sizeof(int), stream);
    count_deg_k<<<(Ee + 255) / 256, 256, 0, stream>>>(dstI, cnt, Ee);
    scan1_k<<<nb, 256, 0, stream>>>(cnt, rowptr, bsum, Nn);
    scan2_k<<<1, 64, 0, stream>>>(bsum, boff, nb, rowptr + Nn);
    scan3_k<<<(Nn + 255) / 256, 256, 0, stream>>>(rowptr, boff, Nn);
    hipMemsetAsync(cnt, 0, Nn * sizeof(int), stream);
    scatter_k<<<(Ee + 255) / 256, 256, 0, stream>>>(srcI, dstI, rowptr, cnt, csrc, Ee);

    const int mblk = (Nn + 127) / 128;   // 391
    dim3 blk(256);

    gemm_f16_k<1, false, false, float, float><<<dim3(1, mblk), blk, 0, stream>>>(x, Wi, bi, nullptr, h, Nn, HIDC, IN_C);

    int nwaveblk = (Nn + 3) / 4;

    for (int l = 0; l < LAYERS; ++l) {
        const float* Wq_l = Wq + (size_t)l * HIDC * HIDC;
        const float* Wk_l = Wk + (size_t)l * HIDC * HIDC;
        const float* Wv_l = Wv + (size_t)l * HIDC * HIDC;
        const float* Ws_l = Ws_ + (size_t)l * HIDC * HIDC;
        const float* bq_l = bq + (size_t)l * HIDC;
        const float* bk_l = bk + (size_t)l * HIDC;
        const float* bv_l = bv + (size_t)l * HIDC;
        const float* bs_l = bs + (size_t)l * HIDC;
        const float* Wb_l = Wbeta + (size_t)l * 3 * HIDC;
        const float* g_l  = ln_g + (size_t)l * HIDC;
        const float* b_l  = ln_b + (size_t)l * HIDC;
        const float* W1_l = W1 + (size_t)l * 4 * HIDC * HIDC;
        const float* b1_l = b1 + (size_t)l * 4 * HIDC;
        const float* W2_l = W2 + (size_t)l * HIDC * 4 * HIDC;
        const float* b2_l = b2 + (size_t)l * HIDC;

        qkvs_k<<<dim3(mblk), blk, 0, stream>>>(h, Wq_l, Wk_l, Wv_l, Ws_l,
                                               bq_l, bk_l, bv_l, bs_l,
                                               qh, kv, sb, Nn);

        attn_ln_k<<<nwaveblk, blk, 0, stream>>>(qh, kv, rowptr, csrc,
                                                sb, h, Wb_l, g_l, b_l, h2, Nn);

        ffn1_k<<<dim3(mblk), blk, 0, stream>>>(h2, W1_l, b1_l, ffn, Nn);
        gemm_f16_k<0, true, false, _Float16, float><<<dim3(1, mblk), blk, 0, stream>>>(ffn, W2_l, b2_l, h2, h, Nn, HIDC, 4 * HIDC);
    }

    gemm_f16_k<0, false, true, float, float><<<dim3(1, mblk), blk, 0, stream>>>(h, Wo, bo, nullptr, outp, Nn, OUT_C, HIDC);
}